// Round 5
// baseline (128.957 us; speedup 1.0000x reference)
//
#include <hip/hip_runtime.h>

#define HDIM 128
#define BDIM 512
#define PM (BDIM * HDIM)   // 65536 floats per [B,H] matrix
#define NSL_T 16           // teacher K=2048 -> 16 slices of 128
#define NSL_S 6            // student K=768  -> 6 slices of 128

// ---------------- Kernel 1: projection partials, LDS-free.
// grid: (B/8, NSL_T+NSL_S). y<16 -> teacher slice y; y>=16 -> student slice y-16.
// block: 128 threads (h). Each block: one 128-col K-slice x 8 rows.
// F is read at wave-uniform addresses -> scalar loads (s_load_dwordx4), no LDS,
// no VALU cost. W read coalesced per-thread (dword), 8 FMA reuse per element.
__global__ __launch_bounds__(128) void proj_kernel(
    const float* __restrict__ Ft, const float* __restrict__ Fs,
    const float* __restrict__ Wt, const float* __restrict__ Ws,
    float* __restrict__ Ppt, float* __restrict__ Pps)
{
    const int h = threadIdx.x;
    const int row0 = blockIdx.x * 8;

    const float* F; const float* W; float* P; int K, sl;
    if (blockIdx.y < NSL_T) { F = Ft; W = Wt; K = 2048; sl = blockIdx.y;         P = Ppt + (size_t)sl * PM; }
    else                    { F = Fs; W = Ws; K = 768;  sl = blockIdx.y - NSL_T; P = Pps + (size_t)sl * PM; }
    const int c0 = sl * 128;

    float acc[8] = {0.f,0.f,0.f,0.f,0.f,0.f,0.f,0.f};

    #pragma unroll 4
    for (int k4 = 0; k4 < 32; ++k4) {
        const float* wp = W + (size_t)(c0 + 4 * k4) * HDIM + h;
        float w0 = wp[0], w1 = wp[HDIM], w2 = wp[2 * HDIM], w3 = wp[3 * HDIM];
        #pragma unroll
        for (int r = 0; r < 8; ++r) {
            // uniform address (no threadIdx) -> scalar load + broadcast
            const float4 f = *(const float4*)&F[(size_t)(row0 + r) * K + c0 + 4 * k4];
            acc[r] = fmaf(f.x, w0, fmaf(f.y, w1, fmaf(f.z, w2, fmaf(f.w, w3, acc[r]))));
        }
    }
    float* Pr = P + (size_t)row0 * HDIM + h;
    #pragma unroll
    for (int r = 0; r < 8; ++r) Pr[r * HDIM] = acc[r];
}

// ---------------- Kernel 2: slice-sum + bias, then U = P@W1a + b1, V = P@W1b.
// grid: (B/4, 2), block 128. Also zero-inits out[0] (runs before pair_kernel).
__global__ __launch_bounds__(128) void uv_kernel(
    const float* __restrict__ Ppt, const float* __restrict__ Pps,
    const float* __restrict__ bt, const float* __restrict__ bs,
    const float* __restrict__ W1, const float* __restrict__ b1,
    float* __restrict__ Ut, float* __restrict__ Vt,
    float* __restrict__ Us, float* __restrict__ Vs,
    float* __restrict__ out)
{
    if (blockIdx.x == 0 && blockIdx.y == 0 && threadIdx.x == 0)
        out[0] = 0.f;   // zero the atomic target for pair_kernel (stream-ordered)

    const float* Pp; const float* bb; float* U; float* V; int ns;
    if (blockIdx.y == 0) { Pp = Ppt; bb = bt; U = Ut; V = Vt; ns = NSL_T; }
    else                 { Pp = Pps; bb = bs; U = Us; V = Vs; ns = NSL_S; }

    __shared__ alignas(16) float fbuf[4][HDIM];
    const int h = threadIdx.x;
    const int row0 = blockIdx.x * 4;

    #pragma unroll
    for (int r = 0; r < 4; ++r) {
        float acc = bb[h];
        for (int s = 0; s < ns; ++s)
            acc += Pp[(size_t)s * PM + (size_t)(row0 + r) * HDIM + h];
        fbuf[r][h] = acc;
    }
    __syncthreads();

    float au[4] = {0.f, 0.f, 0.f, 0.f};
    float av[4] = {0.f, 0.f, 0.f, 0.f};

    const float4* fb0 = (const float4*)fbuf[0];
    const float4* fb1 = (const float4*)fbuf[1];
    const float4* fb2 = (const float4*)fbuf[2];
    const float4* fb3 = (const float4*)fbuf[3];

    #pragma unroll 2
    for (int c4 = 0; c4 < HDIM / 4; ++c4) {
        float f[4][4];
        *(float4*)f[0] = fb0[c4];
        *(float4*)f[1] = fb1[c4];
        *(float4*)f[2] = fb2[c4];
        *(float4*)f[3] = fb3[c4];
        #pragma unroll
        for (int q = 0; q < 4; ++q) {
            int k = 4 * c4 + q;
            float wu = W1[(size_t)k * HDIM + h];
            float wv = W1[(size_t)(HDIM + k) * HDIM + h];
            #pragma unroll
            for (int r = 0; r < 4; ++r) {
                au[r] = fmaf(f[r][q], wu, au[r]);
                av[r] = fmaf(f[r][q], wv, av[r]);
            }
        }
    }

    float bb1 = b1[h];
    #pragma unroll
    for (int r = 0; r < 4; ++r) {
        U[(size_t)(row0 + r) * HDIM + h] = au[r] + bb1;
        V[(size_t)(row0 + r) * HDIM + h] = av[r];
    }
}

// ---------------- Kernel 3: pairwise relations, 2x2 register blocking,
// one atomicAdd per block onto out (zeroed by uv_kernel).
// grid: (16,16) -> 32x32 pair tiles. block (16,16).
__global__ __launch_bounds__(256) void pair_kernel(
    const float* __restrict__ Ut, const float* __restrict__ Vt,
    const float* __restrict__ Us, const float* __restrict__ Vs,
    const float* __restrict__ W2, const float* __restrict__ b2,
    float* __restrict__ out)
{
    // 32 rows x 16 float4 per chunk, stride 17 -> conflict-free V reads
    __shared__ alignas(16) float4 tUt[32 * 17];
    __shared__ alignas(16) float4 tVt[32 * 17];
    __shared__ alignas(16) float4 tUs[32 * 17];
    __shared__ alignas(16) float4 tVs[32 * 17];
    __shared__ alignas(16) float4 w2s[32];
    __shared__ float red[256];

    const int tx = threadIdx.x, ty = threadIdx.y;
    const int tid = ty * 16 + tx;
    const int i0 = blockIdx.y * 32, j0 = blockIdx.x * 32;

    const float4* Ut4 = (const float4*)Ut;
    const float4* Vt4 = (const float4*)Vt;
    const float4* Us4 = (const float4*)Us;
    const float4* Vs4 = (const float4*)Vs;

    if (tid < 32) w2s[tid] = ((const float4*)W2)[tid];

    float aT[2][2] = {{0.f, 0.f}, {0.f, 0.f}};
    float aS[2][2] = {{0.f, 0.f}, {0.f, 0.f}};

    for (int half = 0; half < 2; ++half) {
        const int c0 = half * 16;
        __syncthreads();
        #pragma unroll
        for (int it = 0; it < 2; ++it) {
            int fi = tid + 256 * it;           // 0..511
            int r = fi >> 4, c = fi & 15;      // 32 rows x 16 float4
            tUt[r * 17 + c] = Ut4[(size_t)(i0 + r) * 32 + c0 + c];
            tVt[r * 17 + c] = Vt4[(size_t)(j0 + r) * 32 + c0 + c];
            tUs[r * 17 + c] = Us4[(size_t)(i0 + r) * 32 + c0 + c];
            tVs[r * 17 + c] = Vs4[(size_t)(j0 + r) * 32 + c0 + c];
        }
        __syncthreads();

        #pragma unroll 4
        for (int h4 = 0; h4 < 16; ++h4) {
            float4 w = w2s[c0 + h4];
            float4 u[2], v[2], p[2], q[2];
            u[0] = tUt[ty * 17 + h4];        u[1] = tUt[(ty + 16) * 17 + h4];
            v[0] = tVt[tx * 17 + h4];        v[1] = tVt[(tx + 16) * 17 + h4];
            p[0] = tUs[ty * 17 + h4];        p[1] = tUs[(ty + 16) * 17 + h4];
            q[0] = tVs[tx * 17 + h4];        q[1] = tVs[(tx + 16) * 17 + h4];
            #pragma unroll
            for (int a = 0; a < 2; ++a)
                #pragma unroll
                for (int b = 0; b < 2; ++b) {
                    aT[a][b] = fmaf(fmaxf(u[a].x + v[b].x, 0.f), w.x,
                               fmaf(fmaxf(u[a].y + v[b].y, 0.f), w.y,
                               fmaf(fmaxf(u[a].z + v[b].z, 0.f), w.z,
                               fmaf(fmaxf(u[a].w + v[b].w, 0.f), w.w, aT[a][b]))));
                    aS[a][b] = fmaf(fmaxf(p[a].x + q[b].x, 0.f), w.x,
                               fmaf(fmaxf(p[a].y + q[b].y, 0.f), w.y,
                               fmaf(fmaxf(p[a].z + q[b].z, 0.f), w.z,
                               fmaf(fmaxf(p[a].w + q[b].w, 0.f), w.w, aS[a][b]))));
                }
        }
    }

    const float b2v = b2[0];
    float local = 0.f;
    #pragma unroll
    for (int a = 0; a < 2; ++a)
        #pragma unroll
        for (int b = 0; b < 2; ++b) {
            int i = i0 + ty + 16 * a;
            int j = j0 + tx + 16 * b;
            if (i != j) {
                float tr = 1.f / (1.f + __expf(-(aT[a][b] + b2v)));
                float sr = 1.f / (1.f + __expf(-(aS[a][b] + b2v)));
                float d = sr - tr;
                local = fmaf(d, d, local);
            }
        }

    red[tid] = local;
    __syncthreads();
    #pragma unroll
    for (int s = 128; s > 0; s >>= 1) {
        if (tid < s) red[tid] += red[tid + s];
        __syncthreads();
    }
    if (tid == 0)
        atomicAdd(out, red[0] * (1.0f / ((float)BDIM * (float)BDIM)));
}

extern "C" void kernel_launch(void* const* d_in, const int* in_sizes, int n_in,
                              void* d_out, int out_size, void* d_ws, size_t ws_size,
                              hipStream_t stream) {
    const float* teacher = (const float*)d_in[0];   // [512,2048]
    const float* student = (const float*)d_in[1];   // [512,768]
    const float* Wt = (const float*)d_in[2];        // [2048,128]
    const float* bt = (const float*)d_in[3];        // [128]
    const float* Ws = (const float*)d_in[4];        // [768,128]
    const float* bs = (const float*)d_in[5];        // [128]
    const float* W1 = (const float*)d_in[6];        // [256,128]
    const float* b1 = (const float*)d_in[7];        // [128]
    const float* W2 = (const float*)d_in[8];        // [128,1]
    const float* b2 = (const float*)d_in[9];        // [1]
    float* out = (float*)d_out;

    float* ws = (float*)d_ws;
    float* Ppt = ws;                        // [16][512][128]
    float* Pps = Ppt + (size_t)NSL_T * PM;  // [6][512][128]
    float* Ut  = Pps + (size_t)NSL_S * PM;
    float* Vt  = Ut + PM;
    float* Us  = Vt + PM;
    float* Vs  = Us + PM;

    proj_kernel<<<dim3(BDIM / 8, NSL_T + NSL_S), 128, 0, stream>>>(
        teacher, student, Wt, Ws, Ppt, Pps);

    uv_kernel<<<dim3(BDIM / 4, 2), 128, 0, stream>>>(Ppt, Pps, bt, bs, W1, b1,
                                                     Ut, Vt, Us, Vs, out);

    pair_kernel<<<dim3(16, 16), dim3(16, 16), 0, stream>>>(
        Ut, Vt, Us, Vs, W2, b2, out);
}

// Round 6
// 98.558 us; speedup vs baseline: 1.3084x; 1.3084x over previous
//
#include <hip/hip_runtime.h>

#define HDIM 128
#define BDIM 512

typedef __attribute__((ext_vector_type(8))) __bf16 bf16x8;
typedef __attribute__((ext_vector_type(4))) float  f32x4;

// ---------------- Kernel 1: P = F @ W via bf16 MFMA, K-split x4 waves/tile.
// grid: 512 blocks x 256 thr. bid = net*256 + mtile*8 + ntile.
// Each wave does K/4; block LDS-reduces the 4 partials, stores P as bf16.
// Layouts (gfx950 16x16x32_bf16, HW-verified m89/m91/m120):
//   A[m][k]: m = lane&15, k = (lane>>4)*8 + j
//   B[k][n]: n = lane&15, k = (lane>>4)*8 + j
//   D[row][col]: col = lane&15, row = (lane>>4)*4 + reg
__global__ __launch_bounds__(256) void proj_mfma(
    const float* __restrict__ Ft, const float* __restrict__ Fs,
    const float* __restrict__ Wt, const float* __restrict__ Ws,
    __bf16* __restrict__ Pbt, __bf16* __restrict__ Pbs)
{
    const int tid = threadIdx.x;
    const int wv = tid >> 6, l = tid & 63;
    const int t = blockIdx.x;
    const int net = t >> 8;
    const int mtile = (t >> 3) & 31, ntile = t & 7;

    const float* F; const float* W; __bf16* P; int K;
    if (net == 0) { F = Ft; W = Wt; P = Pbt; K = 2048; }
    else          { F = Fs; W = Ws; P = Pbs; K = 768;  }

    const int m0 = mtile * 16, n0 = ntile * 16;
    const int Ks = K >> 2;                 // 512 or 192 (both %32==0)
    const int q = l >> 4, ln = l & 15;
    const int arow = m0 + ln;
    const int bn = n0 + ln;

    f32x4 acc = {0.f, 0.f, 0.f, 0.f};
    for (int k0 = wv * Ks; k0 < (wv + 1) * Ks; k0 += 32) {
        const int ka = k0 + q * 8;
        const float4 fa0 = *(const float4*)&F[(size_t)arow * K + ka];
        const float4 fa1 = *(const float4*)&F[(size_t)arow * K + ka + 4];
        bf16x8 a, b;
        a[0] = (__bf16)fa0.x; a[1] = (__bf16)fa0.y; a[2] = (__bf16)fa0.z; a[3] = (__bf16)fa0.w;
        a[4] = (__bf16)fa1.x; a[5] = (__bf16)fa1.y; a[6] = (__bf16)fa1.z; a[7] = (__bf16)fa1.w;
        #pragma unroll
        for (int j = 0; j < 8; ++j)
            b[j] = (__bf16)W[(size_t)(ka + j) * HDIM + bn];
        acc = __builtin_amdgcn_mfma_f32_16x16x32_bf16(a, b, acc, 0, 0, 0);
    }

    __shared__ float lds[4 * 256];
    #pragma unroll
    for (int r = 0; r < 4; ++r) lds[wv * 256 + r * 64 + l] = acc[r];
    __syncthreads();

    // tid = r*64 + l2 position; sum 4 wave partials, store bf16.
    {
        const float s = lds[tid] + lds[256 + tid] + lds[512 + tid] + lds[768 + tid];
        const int r = tid >> 6, l2 = tid & 63;
        const int row = m0 + ((l2 >> 4) << 2) + r;
        const int col = n0 + (l2 & 15);
        P[(size_t)row * HDIM + col] = (__bf16)s;
    }
}

// ---------------- Kernel 2: U/V = Pb @ W1 (+ analytic bias term) via MFMA.
// grid: 1024 blocks x 64 thr. bid = net*512 + uvh*256 + mtile*8 + ntile.
// Bias fold: U[i,h] = (P@W1a)[i,h] + c[h],  c = b^T@W1a + b1 (row-independent).
// cpart accumulated from the same W1 values loaded for B-frags, quad-reduced
// via 2x shfl_xor.
__global__ __launch_bounds__(64) void uv_mfma(
    const __bf16* __restrict__ Pbt, const __bf16* __restrict__ Pbs,
    const float* __restrict__ bt, const float* __restrict__ bs,
    const float* __restrict__ W1, const float* __restrict__ b1,
    float* __restrict__ Ut, float* __restrict__ Vt,
    float* __restrict__ Us, float* __restrict__ Vs,
    float* __restrict__ out)
{
    const int t = blockIdx.x;
    const int net = t >> 9, uvh = (t >> 8) & 1;
    const int mtile = (t >> 3) & 31, ntile = t & 7;
    const int l = threadIdx.x;

    if (t == 0 && l == 0) out[0] = 0.f;   // zero atomic target for pair_kernel

    const __bf16* P   = net ? Pbs : Pbt;
    const float* bias = net ? bs : bt;
    float* O = net ? (uvh ? Vs : Us) : (uvh ? Vt : Ut);
    const float* W1o = W1 + (size_t)uvh * HDIM * HDIM;

    const int m0 = mtile * 16, n0 = ntile * 16;
    const int q = l >> 4, ln = l & 15;
    const int arow = m0 + ln, bn = n0 + ln;

    f32x4 acc = {0.f, 0.f, 0.f, 0.f};
    float cpart = 0.f;
    #pragma unroll
    for (int k0 = 0; k0 < HDIM; k0 += 32) {
        const int ka = k0 + q * 8;
        bf16x8 a = *(const bf16x8*)&P[(size_t)arow * HDIM + ka];
        bf16x8 b;
        #pragma unroll
        for (int j = 0; j < 8; ++j) {
            const float w = W1o[(size_t)(ka + j) * HDIM + bn];
            b[j] = (__bf16)w;
            cpart = fmaf(bias[ka + j], w, cpart);
        }
        acc = __builtin_amdgcn_mfma_f32_16x16x32_bf16(a, b, acc, 0, 0, 0);
    }
    cpart += __shfl_xor(cpart, 16, 64);
    cpart += __shfl_xor(cpart, 32, 64);
    const float cfull = cpart + (uvh == 0 ? b1[bn] : 0.f);

    #pragma unroll
    for (int r = 0; r < 4; ++r) {
        const int row = m0 + q * 4 + r;
        O[(size_t)row * HDIM + bn] = acc[r] + cfull;
    }
}

// ---------------- Kernel 3: pairwise relations, 2x2 register blocking,
// one atomicAdd per block onto out (zeroed by uv_mfma). Unchanged from R4.
__global__ __launch_bounds__(256) void pair_kernel(
    const float* __restrict__ Ut, const float* __restrict__ Vt,
    const float* __restrict__ Us, const float* __restrict__ Vs,
    const float* __restrict__ W2, const float* __restrict__ b2,
    float* __restrict__ out)
{
    __shared__ alignas(16) float4 tUt[32 * 17];
    __shared__ alignas(16) float4 tVt[32 * 17];
    __shared__ alignas(16) float4 tUs[32 * 17];
    __shared__ alignas(16) float4 tVs[32 * 17];
    __shared__ alignas(16) float4 w2s[32];
    __shared__ float red[256];

    const int tx = threadIdx.x, ty = threadIdx.y;
    const int tid = ty * 16 + tx;
    const int i0 = blockIdx.y * 32, j0 = blockIdx.x * 32;

    const float4* Ut4 = (const float4*)Ut;
    const float4* Vt4 = (const float4*)Vt;
    const float4* Us4 = (const float4*)Us;
    const float4* Vs4 = (const float4*)Vs;

    if (tid < 32) w2s[tid] = ((const float4*)W2)[tid];

    float aT[2][2] = {{0.f, 0.f}, {0.f, 0.f}};
    float aS[2][2] = {{0.f, 0.f}, {0.f, 0.f}};

    for (int half = 0; half < 2; ++half) {
        const int c0 = half * 16;
        __syncthreads();
        #pragma unroll
        for (int it = 0; it < 2; ++it) {
            int fi = tid + 256 * it;
            int r = fi >> 4, c = fi & 15;
            tUt[r * 17 + c] = Ut4[(size_t)(i0 + r) * 32 + c0 + c];
            tVt[r * 17 + c] = Vt4[(size_t)(j0 + r) * 32 + c0 + c];
            tUs[r * 17 + c] = Us4[(size_t)(i0 + r) * 32 + c0 + c];
            tVs[r * 17 + c] = Vs4[(size_t)(j0 + r) * 32 + c0 + c];
        }
        __syncthreads();

        #pragma unroll 4
        for (int h4 = 0; h4 < 16; ++h4) {
            float4 w = w2s[c0 + h4];
            float4 u[2], v[2], p[2], q[2];
            u[0] = tUt[ty * 17 + h4];        u[1] = tUt[(ty + 16) * 17 + h4];
            v[0] = tVt[tx * 17 + h4];        v[1] = tVt[(tx + 16) * 17 + h4];
            p[0] = tUs[ty * 17 + h4];        p[1] = tUs[(ty + 16) * 17 + h4];
            q[0] = tVs[tx * 17 + h4];        q[1] = tVs[(tx + 16) * 17 + h4];
            #pragma unroll
            for (int a = 0; a < 2; ++a)
                #pragma unroll
                for (int b = 0; b < 2; ++b) {
                    aT[a][b] = fmaf(fmaxf(u[a].x + v[b].x, 0.f), w.x,
                               fmaf(fmaxf(u[a].y + v[b].y, 0.f), w.y,
                               fmaf(fmaxf(u[a].z + v[b].z, 0.f), w.z,
                               fmaf(fmaxf(u[a].w + v[b].w, 0.f), w.w, aT[a][b]))));
                    aS[a][b] = fmaf(fmaxf(p[a].x + q[b].x, 0.f), w.x,
                               fmaf(fmaxf(p[a].y + q[b].y, 0.f), w.y,
                               fmaf(fmaxf(p[a].z + q[b].z, 0.f), w.z,
                               fmaf(fmaxf(p[a].w + q[b].w, 0.f), w.w, aS[a][b]))));
                }
        }
    }

    const float b2v = b2[0];
    float local = 0.f;
    #pragma unroll
    for (int a = 0; a < 2; ++a)
        #pragma unroll
        for (int b = 0; b < 2; ++b) {
            int i = i0 + ty + 16 * a;
            int j = j0 + tx + 16 * b;
            if (i != j) {
                float tr = 1.f / (1.f + __expf(-(aT[a][b] + b2v)));
                float sr = 1.f / (1.f + __expf(-(aS[a][b] + b2v)));
                float d = sr - tr;
                local = fmaf(d, d, local);
            }
        }

    red[tid] = local;
    __syncthreads();
    #pragma unroll
    for (int s = 128; s > 0; s >>= 1) {
        if (tid < s) red[tid] += red[tid + s];
        __syncthreads();
    }
    if (tid == 0)
        atomicAdd(out, red[0] * (1.0f / ((float)BDIM * (float)BDIM)));
}

extern "C" void kernel_launch(void* const* d_in, const int* in_sizes, int n_in,
                              void* d_out, int out_size, void* d_ws, size_t ws_size,
                              hipStream_t stream) {
    const float* teacher = (const float*)d_in[0];   // [512,2048]
    const float* student = (const float*)d_in[1];   // [512,768]
    const float* Wt = (const float*)d_in[2];        // [2048,128]
    const float* bt = (const float*)d_in[3];        // [128]
    const float* Ws = (const float*)d_in[4];        // [768,128]
    const float* bs = (const float*)d_in[5];        // [128]
    const float* W1 = (const float*)d_in[6];        // [256,128]
    const float* b1 = (const float*)d_in[7];        // [128]
    const float* W2 = (const float*)d_in[8];        // [128,1]
    const float* b2 = (const float*)d_in[9];        // [1]
    float* out = (float*)d_out;

    const size_t M = (size_t)BDIM * HDIM;           // 65536 elements
    __bf16* Pbt = (__bf16*)d_ws;                    // [512][128] bf16
    __bf16* Pbs = Pbt + M;
    float* Ut = (float*)(Pbs + M);
    float* Vt = Ut + M;
    float* Us = Vt + M;
    float* Vs = Us + M;

    proj_mfma<<<512, 256, 0, stream>>>(teacher, student, Wt, Ws, Pbt, Pbs);

    uv_mfma<<<1024, 64, 0, stream>>>(Pbt, Pbs, bt, bs, W1, b1,
                                     Ut, Vt, Us, Vs, out);

    pair_kernel<<<dim3(16, 16), dim3(16, 16), 0, stream>>>(
        Ut, Vt, Us, Vs, W2, b2, out);
}